// Round 11
// baseline (132.147 us; speedup 1.0000x reference)
//
#include <hip/hip_runtime.h>
#include <math.h>

#define NB  4
#define NLQ 256
#define NLK 512
#define NH  256

// scale folded into projections: exp2(SC*(q+k)) = exp(2*(q+k))
#define SCALE_2LOG2E 2.885390081777927f
#define LOG2E        1.4426950408889634f

// ---------------------------------------------------------------------------
// Setup: W transposes (blocks 0..31) + per-batch mask compaction (32..35).
// ---------------------------------------------------------------------------
__global__ __launch_bounds__(256) void setup_kernel(
    const float* __restrict__ Wq, const float* __restrict__ Wk,
    const int* __restrict__ mask,
    float* __restrict__ Wtq, float* __restrict__ Wtk,
    int* __restrict__ act, int* __restrict__ nact)
{
    const int blk = blockIdx.x;
    const int t   = threadIdx.x;

    if (blk < 32) {
        __shared__ float ts[64][65];
        const int m    = blk >> 4;               // 0: Wq, 1: Wk
        const int tile = blk & 15;
        const int h0 = (tile >> 2) * 64;
        const int c0 = (tile & 3) * 64;
        const float* W  = m ? Wk  : Wq;
        float*       Wt = m ? Wtk : Wtq;
        const int lr = t >> 4, lc = t & 15;
        #pragma unroll
        for (int i = 0; i < 4; ++i) {
            const int r = lr + 16 * i;
            const float4 d = *(const float4*)(W + (size_t)(h0 + r) * NH + c0 + lc * 4);
            ts[r][lc * 4 + 0] = d.x;
            ts[r][lc * 4 + 1] = d.y;
            ts[r][lc * 4 + 2] = d.z;
            ts[r][lc * 4 + 3] = d.w;
        }
        __syncthreads();
        #pragma unroll
        for (int i = 0; i < 4; ++i) {
            const int c = lr + 16 * i;
            float4 d;
            d.x = ts[lc * 4 + 0][c];
            d.y = ts[lc * 4 + 1][c];
            d.z = ts[lc * 4 + 2][c];
            d.w = ts[lc * 4 + 3][c];
            *(float4*)(Wt + (size_t)(c0 + c) * NH + h0 + lc * 4) = d;
        }
    } else if (blk < 32 + NB) {
        const int b = blk - 32;
        __shared__ int wcnt[8], wpre[9];
        const int lane = t & 63, wave = t >> 6;
        const int k1 = t, k2 = t + 256;
        const int m1 = mask[b * NLK + k1];
        const int m2 = mask[b * NLK + k2];
        const unsigned long long below = (1ULL << lane) - 1ULL;
        const unsigned long long bal1 = __ballot(m1 != 0);
        const unsigned long long bal2 = __ballot(m2 != 0);
        const int r1 = __popcll(bal1 & below);
        const int r2 = __popcll(bal2 & below);
        if (lane == 0) { wcnt[wave] = __popcll(bal1); wcnt[4 + wave] = __popcll(bal2); }
        __syncthreads();
        if (t == 0) {
            int s = 0;
            #pragma unroll
            for (int w = 0; w < 8; ++w) { wpre[w] = s; s += wcnt[w]; }
            wpre[8] = s;
        }
        __syncthreads();
        const int na = wpre[8];
        if (m1) act[b * NLK + wpre[wave]     + r1] = k1;
        if (m2) act[b * NLK + wpre[4 + wave] + r2] = k2;
        if (k1 >= na) act[b * NLK + k1] = 0;     // safe tail
        if (k2 >= na) act[b * NLK + k2] = 0;
        if (t == 0) nact[b] = na;
    }
}

// ---------------------------------------------------------------------------
// Fused projections (c-split across waves, coalesced Wt loads).
// Blocks 0..255: q rows (4/block) -> qp (scaled).
// Blocks 256..767: compact k slots (4/block, gathered via act) -> kp_ct
//   [b][h][j] compact-TRANSPOSED (scaled), so attn reads coalesce.
// ---------------------------------------------------------------------------
__global__ __launch_bounds__(256) void prep_kernel(
    const float* __restrict__ query, const float* __restrict__ key,
    const float* __restrict__ Wtq, const float* __restrict__ bq,
    const float* __restrict__ Wtk, const float* __restrict__ bk,
    const int* __restrict__ act, const int* __restrict__ nact,
    float* __restrict__ qp, float* __restrict__ kp_ct)
{
    const int blk  = blockIdx.x;
    const int t    = threadIdx.x;
    const int wave = t >> 6;
    const int lane = t & 63;

    __shared__ float  xs[4][NH];
    __shared__ float4 ps[4][4][64];
    __shared__ int    ridx[4];

    const float *Wt, *bias;
    int b = 0, j0 = 0, r0 = 0, na = 0;
    const bool isq = (blk < NB * NLQ / 4);

    if (isq) {
        r0 = blk * 4;
        ((float4*)&xs[0][0])[t] = ((const float4*)(query + (size_t)r0 * NH))[t];
        Wt = Wtq; bias = bq;
    } else {
        b  = (blk - 256) >> 7;
        j0 = ((blk - 256) & 127) * 4;
        na = nact[b];
        if (j0 >= na) return;
        if (t < 4) ridx[t] = act[b * NLK + ((j0 + t < na) ? (j0 + t) : j0)];
        __syncthreads();
        const int r = t >> 6, c4 = t & 63;
        ((float4*)xs[r])[c4] =
            ((const float4*)(key + ((size_t)b * NLK + ridx[r]) * NH))[c4];
        Wt = Wtk; bias = bk;
    }
    __syncthreads();

    float4 acc[4];
    #pragma unroll
    for (int r = 0; r < 4; ++r) acc[r] = (float4){0.f, 0.f, 0.f, 0.f};

    const int cbase = wave * 64;
    #pragma unroll 4
    for (int cc = 0; cc < 64; ++cc) {
        const int c = cbase + cc;
        const float4 w = *(const float4*)(Wt + (size_t)c * NH + lane * 4);
        #pragma unroll
        for (int r = 0; r < 4; ++r) {
            const float xv = xs[r][c];             // LDS broadcast
            acc[r].x = fmaf(xv, w.x, acc[r].x);
            acc[r].y = fmaf(xv, w.y, acc[r].y);
            acc[r].z = fmaf(xv, w.z, acc[r].z);
            acc[r].w = fmaf(xv, w.w, acc[r].w);
        }
    }
    #pragma unroll
    for (int r = 0; r < 4; ++r) ps[wave][r][lane] = acc[r];
    __syncthreads();

    const int r = wave, l = lane;
    const float4 p0 = ps[0][r][l], p1 = ps[1][r][l];
    const float4 p2 = ps[2][r][l], p3 = ps[3][r][l];
    const float4 bb = *(const float4*)(bias + l * 4);
    float4 o;
    o.x = (p0.x + p1.x + p2.x + p3.x + bb.x) * SCALE_2LOG2E;
    o.y = (p0.y + p1.y + p2.y + p3.y + bb.y) * SCALE_2LOG2E;
    o.z = (p0.z + p1.z + p2.z + p3.z + bb.z) * SCALE_2LOG2E;
    o.w = (p0.w + p1.w + p2.w + p3.w + bb.w) * SCALE_2LOG2E;

    if (isq) {
        *(float4*)(qp + (size_t)(r0 + r) * NH + l * 4) = o;
    } else if (j0 + r < na) {
        const int j = j0 + r;
        kp_ct[((size_t)b * NH + l * 4 + 0) * NLK + j] = o.x;
        kp_ct[((size_t)b * NH + l * 4 + 1) * NLK + j] = o.y;
        kp_ct[((size_t)b * NH + l * 4 + 2) * NLK + j] = o.z;
        kp_ct[((size_t)b * NH + l * 4 + 3) * NLK + j] = o.w;
    }
}

// ---------------------------------------------------------------------------
// 2 sigmoid-units sharing one k value across two q rows.
// ---------------------------------------------------------------------------
__device__ __forceinline__ void sig2(const float4 q, const float kx,
                                     float& a0, float& a1) {
    const float e0 = __builtin_amdgcn_exp2f(q.x + kx);
    a0 = fmaf(q.z, __builtin_amdgcn_rcpf(e0 + 1.f), a0);
    const float e1 = __builtin_amdgcn_exp2f(q.y + kx);
    a1 = fmaf(q.z, __builtin_amdgcn_rcpf(e1 + 1.f), a1);
}

// ---------------------------------------------------------------------------
// Fused attn. Grid = 512 (one q-PAIR per block), 512 threads (8 waves),
// __launch_bounds__(512,4) -> 128-reg cap (no spill), 2 blocks/CU.
// Scores: lane <-> slot-quad 4*lane, wave <-> 32-c chunk; group = 2 c-steps:
// 2x float4 kx + 2x float4 qv {q0',q1',v} -> 16 sigmoid units per 2 global
// loads (q-reuse!), 8 acc chains. 8-way c-chunk combine via LDS.
// out_w: softmax -> compact weights -> LDS scatter to original order ->
// ONE coalesced contiguous write per row (no scattered global writes).
// Output GEMV: value loads shared across both q rows.
// score'(q,k) = -2*sum_h v[h]*rcp(exp2(q'+k')+1)  (softmax shift-invariant)
// ---------------------------------------------------------------------------
__global__ __launch_bounds__(512, 4) void attn_kernel(
    const float* __restrict__ qp, const float* __restrict__ kp_ct,
    const float* __restrict__ value,
    const int* __restrict__ act, const int* __restrict__ nact,
    const float* __restrict__ vvec,
    float* __restrict__ out_o, float* __restrict__ out_w)
{
    __shared__ __align__(16) float  sc0[NLK], sc1[NLK];   // compact scores/weights
    __shared__ __align__(16) int    actl[NLK];
    __shared__ float4 qv[NH];            // {q0', q1', v, 0}
    __shared__ float4 ps0[512], ps1[512];// score partials (aliased as wf below)
    __shared__ float  ph0[512], ph1[512];// output partials

    const int blk  = blockIdx.x;
    const int b    = blk >> 7;           // 128 blocks per batch
    const int q0   = (blk & 127) * 2;
    const int t    = threadIdx.x;        // 0..511
    const int lane = t & 63;
    const int wave = t >> 6;

    const int na = nact[b];
    actl[t] = act[b * NLK + t];          // safe 0 tail from setup

    if (t < NH) {
        const float* qr = qp + (size_t)(b * NLQ + q0) * NH;
        qv[t] = make_float4(qr[t], qr[NH + t], vvec[t], 0.f);
    }
    __syncthreads();

    const int cb = wave * 32;            // this wave's c-chunk
    const float* kbase = kp_ct + (size_t)b * NH * NLK + (size_t)cb * NLK;

    // ---- scores pass 1: slot-quad 4*lane (slots 0..255) ----
    float4 acc0 = {0.f, 0.f, 0.f, 0.f};
    float4 acc1 = {0.f, 0.f, 0.f, 0.f};
    if (4 * lane < na) {
        const float* kptr = kbase + 4 * lane;
        #pragma unroll 4
        for (int g = 0; g < 16; ++g) {   // 16 groups of 2 c
            const float4 kx0 = *(const float4*)(kptr);
            const float4 kx1 = *(const float4*)(kptr + NLK);
            const int c0 = cb + 2 * g;
            const float4 qA = qv[c0];
            const float4 qB = qv[c0 + 1];
            sig2(qA, kx0.x, acc0.x, acc1.x);
            sig2(qA, kx0.y, acc0.y, acc1.y);
            sig2(qA, kx0.z, acc0.z, acc1.z);
            sig2(qA, kx0.w, acc0.w, acc1.w);
            sig2(qB, kx1.x, acc0.x, acc1.x);
            sig2(qB, kx1.y, acc0.y, acc1.y);
            sig2(qB, kx1.z, acc0.z, acc1.z);
            sig2(qB, kx1.w, acc0.w, acc1.w);
            kptr += 2 * NLK;
        }
    }
    ps0[t] = acc0;
    ps1[t] = acc1;
    __syncthreads();
    if (t < 64) {                        // combine 8 c-chunks, slot-quad t
        float4 s0 = ps0[t], s1 = ps1[t];
        #pragma unroll
        for (int w = 1; w < 8; ++w) {
            const float4 u0 = ps0[t + 64 * w];
            const float4 u1 = ps1[t + 64 * w];
            s0.x += u0.x; s0.y += u0.y; s0.z += u0.z; s0.w += u0.w;
            s1.x += u1.x; s1.y += u1.y; s1.z += u1.z; s1.w += u1.w;
        }
        const int j = 4 * t;
        sc0[j + 0] = (j + 0 < na) ? -2.f * s0.x : -INFINITY;
        sc0[j + 1] = (j + 1 < na) ? -2.f * s0.y : -INFINITY;
        sc0[j + 2] = (j + 2 < na) ? -2.f * s0.z : -INFINITY;
        sc0[j + 3] = (j + 3 < na) ? -2.f * s0.w : -INFINITY;
        sc1[j + 0] = (j + 0 < na) ? -2.f * s1.x : -INFINITY;
        sc1[j + 1] = (j + 1 < na) ? -2.f * s1.y : -INFINITY;
        sc1[j + 2] = (j + 2 < na) ? -2.f * s1.z : -INFINITY;
        sc1[j + 3] = (j + 3 < na) ? -2.f * s1.w : -INFINITY;
    }
    __syncthreads();

    // ---- scores pass 2: overflow slots 256..na (block-uniform branch) ----
    if (na > 256) {
        float4 a2 = {0.f, 0.f, 0.f, 0.f};
        float4 b2 = {0.f, 0.f, 0.f, 0.f};
        const int s0 = 256 + 4 * lane;
        if (s0 < na) {
            const float* kptr = kbase + s0;
            #pragma unroll 4
            for (int g = 0; g < 16; ++g) {
                const float4 kx0 = *(const float4*)(kptr);
                const float4 kx1 = *(const float4*)(kptr + NLK);
                const int c0 = cb + 2 * g;
                const float4 qA = qv[c0];
                const float4 qB = qv[c0 + 1];
                sig2(qA, kx0.x, a2.x, b2.x);
                sig2(qA, kx0.y, a2.y, b2.y);
                sig2(qA, kx0.z, a2.z, b2.z);
                sig2(qA, kx0.w, a2.w, b2.w);
                sig2(qB, kx1.x, a2.x, b2.x);
                sig2(qB, kx1.y, a2.y, b2.y);
                sig2(qB, kx1.z, a2.z, b2.z);
                sig2(qB, kx1.w, a2.w, b2.w);
                kptr += 2 * NLK;
            }
        }
        ps0[t] = a2;
        ps1[t] = b2;
        __syncthreads();
        if (t < 64) {
            float4 s0s = ps0[t], s1s = ps1[t];
            #pragma unroll
            for (int w = 1; w < 8; ++w) {
                const float4 u0 = ps0[t + 64 * w];
                const float4 u1 = ps1[t + 64 * w];
                s0s.x += u0.x; s0s.y += u0.y; s0s.z += u0.z; s0s.w += u0.w;
                s1s.x += u1.x; s1s.y += u1.y; s1s.z += u1.z; s1s.w += u1.w;
            }
            const int j = 256 + 4 * t;
            sc0[j + 0] = (j + 0 < na) ? -2.f * s0s.x : -INFINITY;
            sc0[j + 1] = (j + 1 < na) ? -2.f * s0s.y : -INFINITY;
            sc0[j + 2] = (j + 2 < na) ? -2.f * s0s.z : -INFINITY;
            sc0[j + 3] = (j + 3 < na) ? -2.f * s0s.w : -INFINITY;
            sc1[j + 0] = (j + 0 < na) ? -2.f * s1s.x : -INFINITY;
            sc1[j + 1] = (j + 1 < na) ? -2.f * s1s.y : -INFINITY;
            sc1[j + 2] = (j + 2 < na) ? -2.f * s1s.z : -INFINITY;
            sc1[j + 3] = (j + 3 < na) ? -2.f * s1s.w : -INFINITY;
        }
    } else {
        if (t < 256) { sc0[256 + t] = -INFINITY; sc1[256 + t] = -INFINITY; }
    }
    __syncthreads();

    // ---- zero original-order weight rows (alias of ps0/ps1) ----
    float* wf0 = (float*)ps0;            // 512 floats
    float* wf1 = (float*)ps1;
    wf0[t] = 0.f;
    wf1[t] = 0.f;
    __syncthreads();

    // ---- softmax: wave 0 -> row 0, wave 1 -> row 1 (512 compact slots) ----
    if (wave < 2) {
        float* row = wave ? sc1 : sc0;
        float vals[8];
        float m = -INFINITY;
        #pragma unroll
        for (int j8 = 0; j8 < 8; ++j8) {
            vals[j8] = row[lane + j8 * 64];
            m = fmaxf(m, vals[j8]);
        }
        #pragma unroll
        for (int s = 32; s >= 1; s >>= 1)
            m = fmaxf(m, __shfl_xor(m, s, 64));
        float sum = 0.0f;
        #pragma unroll
        for (int j8 = 0; j8 < 8; ++j8) {
            vals[j8] = __builtin_amdgcn_exp2f((vals[j8] - m) * LOG2E);
            sum += vals[j8];
        }
        #pragma unroll
        for (int s = 32; s >= 1; s >>= 1)
            sum += __shfl_xor(sum, s, 64);
        const float inv = __builtin_amdgcn_rcpf(sum);
        float* wf = wave ? wf1 : wf0;
        #pragma unroll
        for (int j8 = 0; j8 < 8; ++j8) {
            const int jj = lane + j8 * 64;
            const float w = vals[j8] * inv;
            row[jj] = w;                        // 0 for jj >= na
            if (jj < na) wf[actl[jj]] = w;      // LDS scatter to orig order
        }
    }
    __syncthreads();

    // ---- out_w: one coalesced contiguous write per row ----
    out_w[(size_t)(b * NLQ + q0)     * NLK + t] = wf0[t];
    out_w[(size_t)(b * NLQ + q0 + 1) * NLK + t] = wf1[t];

    // ---- output: thread t -> h = t&255, j-half t>>8; value loads shared ----
    {
        const int h    = t & 255;
        const int half = t >> 8;
        const int n4   = (na + 3) >> 2;
        const int lo   = half * 64;
        const int hi   = (n4 < lo + 64) ? n4 : (lo + 64);
        const float* vb = value + (size_t)b * NLK * NH + h;
        float o0 = 0.f, o1 = 0.f;
        int j4 = lo;
        for (; j4 + 2 <= hi; j4 += 2) {
            const float4 w00 = ((const float4*)sc0)[j4];
            const float4 w01 = ((const float4*)sc0)[j4 + 1];
            const float4 w10 = ((const float4*)sc1)[j4];
            const float4 w11 = ((const float4*)sc1)[j4 + 1];
            const int4   a0  = ((const int4*)actl)[j4];
            const int4   a1  = ((const int4*)actl)[j4 + 1];
            const float v0 = vb[(size_t)a0.x * NH];   // 8 batched loads,
            const float v1 = vb[(size_t)a0.y * NH];   // each feeds 2 q rows
            const float v2 = vb[(size_t)a0.z * NH];
            const float v3 = vb[(size_t)a0.w * NH];
            const float v4 = vb[(size_t)a1.x * NH];
            const float v5 = vb[(size_t)a1.y * NH];
            const float v6 = vb[(size_t)a1.z * NH];
            const float v7 = vb[(size_t)a1.w * NH];
            o0 = fmaf(w00.x, v0, o0); o1 = fmaf(w10.x, v0, o1);
            o0 = fmaf(w00.y, v1, o0); o1 = fmaf(w10.y, v1, o1);
            o0 = fmaf(w00.z, v2, o0); o1 = fmaf(w10.z, v2, o1);
            o0 = fmaf(w00.w, v3, o0); o1 = fmaf(w10.w, v3, o1);
            o0 = fmaf(w01.x, v4, o0); o1 = fmaf(w11.x, v4, o1);
            o0 = fmaf(w01.y, v5, o0); o1 = fmaf(w11.y, v5, o1);
            o0 = fmaf(w01.z, v6, o0); o1 = fmaf(w11.z, v6, o1);
            o0 = fmaf(w01.w, v7, o0); o1 = fmaf(w11.w, v7, o1);
        }
        if (j4 < hi) {
            const float4 w00 = ((const float4*)sc0)[j4];
            const float4 w10 = ((const float4*)sc1)[j4];
            const int4   a0  = ((const int4*)actl)[j4];
            const float v0 = vb[(size_t)a0.x * NH];
            const float v1 = vb[(size_t)a0.y * NH];
            const float v2 = vb[(size_t)a0.z * NH];
            const float v3 = vb[(size_t)a0.w * NH];
            o0 = fmaf(w00.x, v0, o0); o1 = fmaf(w10.x, v0, o1);
            o0 = fmaf(w00.y, v1, o0); o1 = fmaf(w10.y, v1, o1);
            o0 = fmaf(w00.z, v2, o0); o1 = fmaf(w10.z, v2, o1);
            o0 = fmaf(w00.w, v3, o0); o1 = fmaf(w10.w, v3, o1);
        }
        ph0[t] = o0;
        ph1[t] = o1;
    }
    __syncthreads();
    if (t < 256) {
        out_o[(size_t)(b * NLQ + q0)     * NH + t] = ph0[t] + ph0[t + 256];
        out_o[(size_t)(b * NLQ + q0 + 1) * NH + t] = ph1[t] + ph1[t + 256];
    }
}

// ---------------------------------------------------------------------------
extern "C" void kernel_launch(void* const* d_in, const int* in_sizes, int n_in,
                              void* d_out, int out_size, void* d_ws, size_t ws_size,
                              hipStream_t stream) {
    const float* query = (const float*)d_in[0];
    const float* key   = (const float*)d_in[1];
    const float* value = (const float*)d_in[2];
    const int*   mask  = (const int*)  d_in[3];
    const float* Wq    = (const float*)d_in[4];
    const float* bq    = (const float*)d_in[5];
    const float* Wk    = (const float*)d_in[6];
    const float* bk    = (const float*)d_in[7];
    const float* v     = (const float*)d_in[8];
    // d_in[9] (bv) drops out of softmax -> unused

    float* out_o = (float*)d_out;                     // [4,256,256]
    float* out_w = out_o + NB * NLQ * NH;             // [4,256,512]

    float* qp    = (float*)d_ws;                      // [4,256,256] scaled
    float* kp_ct = qp + NB * NLQ * NH;                // [4,256,512] compact-T
    int*   act   = (int*)(kp_ct + NB * NH * NLK);     // [4,512]
    int*   nact  = act + NB * NLK;                    // [4]

    const size_t base = (size_t)(NB * NLQ * NH) + (size_t)(NB * NH * NLK)
                      + NB * NLK + NB;
    float* wtq;
    if (ws_size >= (base + 2 * NH * NH) * sizeof(float)) {
        wtq = (float*)d_ws + base;                    // workspace tail
    } else {
        // park W^T in the out_w tail; attn (after prep) overwrites out_w
        wtq = out_w + (size_t)NB * NLQ * NLK - 2 * NH * NH;
    }
    float* wtk = wtq + NH * NH;

    setup_kernel<<<36, 256, 0, stream>>>(Wq, Wk, mask, wtq, wtk, act, nact);
    prep_kernel<<<NB * NLQ / 4 + NB * NLK / 4, 256, 0, stream>>>(
        query, key, wtq, bq, wtk, bk, act, nact, qp, kp_ct);
    attn_kernel<<<NB * NLQ / 2, 512, 0, stream>>>(
        qp, kp_ct, value, act, nact, v, out_o, out_w);
}